// Round 4
// baseline (366.953 us; speedup 1.0000x reference)
//
#include <hip/hip_runtime.h>
#include <hip/hip_cooperative_groups.h>

namespace cg = cooperative_groups;

// Problem constants (MemoryGraph_15453292331249)
constexpr int N  = 8192;
constexpr int K  = 32;
constexpr int D  = 32;
constexpr int BS = 2;
constexpr int T  = 16;
constexpr int C  = 64;
constexpr int H  = 64;
constexpr int MOD_IN = 5 * D;   // 160
constexpr int STRIDE = 4;
constexpr int NT = T / STRIDE;  // 4 scan steps
constexpr int NPB    = 8;       // 32-lane groups per block
constexpr int HALVES = 2;       // neurons per group
constexpr int GRID   = N / (NPB * HALVES);  // 512 blocks -> needs only 2/CU

__device__ __forceinline__ float sigmoidf_(float x) { return 1.0f / (1.0f + expf(-x)); }

// ===========================================================================
// Cooperative fused kernel: whole op in one dispatch.
// 512 blocks x 256 threads; 32-lane group owns neurons {gid, gid+4096};
// thread (n,d) handles both batches. grid.sync() between scan steps.
// ===========================================================================
__global__ __launch_bounds__(256, 2) void fused_kernel(
    const float* __restrict__ cc,          // (BS,T,C,D)
    const float* __restrict__ h_prev,      // (BS,N,D)
    const float* __restrict__ prev_msgs,   // (BS,N,D)
    const float* __restrict__ trace_prim,  // (BS,N,D)
    const float* __restrict__ trace_key,   // (BS,N,D)
    const float* __restrict__ primitives,  // (N,D)
    const float* __restrict__ key_w,       // (N,D)
    const float* __restrict__ decay_logit, // (N,)
    const float* __restrict__ bw,          // (N,K,D)
    const float* __restrict__ gw,          // (N,4,32)
    const float* __restrict__ fc1_w,       // (N,160,64)
    const float* __restrict__ fc1_b,       // (N,64)
    const float* __restrict__ fc2_w,       // (N,64,3)
    const float* __restrict__ fc2_b,       // (N,3)
    const float* __restrict__ mod_lr_logit,// (1,)
    const int*   __restrict__ conn,        // (N,K)
    float* __restrict__ m0buf,             // (BS,N,D)
    float* __restrict__ m1buf,             // (BS,N,D)
    float* __restrict__ out)               // (BS,T,C,D)
{
    const int t   = threadIdx.x;
    const int sub = t >> 5;
    const int d   = t & 31;
    const int gid = blockIdx.x * NPB + sub;      // 0..4095

    __shared__ __align__(16) float ek_s[NPB][HALVES][2][D];
    __shared__ __align__(16) float rl[NPB][HALVES][2][K];
    __shared__ __align__(16) int   jl[NPB][HALVES][K];

    const float mlr = sigmoidf_(mod_lr_logit[0]);
    float ep[HALVES][2], edc[HALVES][2];

    #pragma unroll
    for (int hf = 0; hf < HALVES; ++hf) {
        const int n = gid + hf * (N / 2);
        const float* f2w = fc2_w + n * (H * 3);

        // per-neuron fc2_w slice zero-check (skip multiply-by-zero; data-driven)
        int nzf = 0;
        #pragma unroll
        for (int i = 0; i < 6; ++i) nzf |= (f2w[i * 32 + d] != 0.0f);
        #pragma unroll
        for (int m = 1; m < 32; m <<= 1) nzf |= __shfl_xor(nzf, m);

        float o3[2][3];
        if (!nzf) {
            #pragma unroll
            for (int o = 0; o < 3; ++o) {
                const float v = fc2_b[n * 3 + o];
                o3[0][o] = v; o3[1][o] = v;
            }
        } else {
            // General path: full fc1 matvec + fc2 (lane computes h=d and h=d+32)
            const float* W = fc1_w + (size_t)n * (MOD_IN * H);
            #pragma unroll
            for (int b = 0; b < 2; ++b) {
                const size_t base = ((size_t)b * N + n) * D + d;
                float mv[5];
                mv[0] = h_prev[base];
                mv[1] = trace_prim[base];
                mv[2] = trace_key[base];
                mv[3] = primitives[n * D + d];
                mv[4] = key_w[n * D + d];
                float acc0 = 0.f, acc1 = 0.f;
                #pragma unroll
                for (int c = 0; c < 5; ++c) {
                    const float mc = mv[c];
                    for (int dp = 0; dp < 32; ++dp) {
                        const float v = __shfl(mc, dp, 32);
                        const float* wr = W + (c * 32 + dp) * H;
                        acc0 += v * wr[d];
                        acc1 += v * wr[d + 32];
                    }
                }
                const float x0 = tanhf(acc0 + fc1_b[n * H + d]);
                const float x1 = tanhf(acc1 + fc1_b[n * H + d + 32]);
                #pragma unroll
                for (int o = 0; o < 3; ++o) {
                    float p = x0 * f2w[d * 3 + o] + x1 * f2w[(d + 32) * 3 + o];
                    #pragma unroll
                    for (int m = 1; m < 32; m <<= 1) p += __shfl_xor(p, m);
                    o3[b][o] = p + fc2_b[n * 3 + o];
                }
            }
        }

        // gates, eff_decay, eff_prim, eff_key
        #pragma unroll
        for (int b = 0; b < 2; ++b) {
            const size_t base = ((size_t)b * N + n) * D + d;
            const float tp = trace_prim[base];
            const float tk = trace_key[base];
            float sp = tp * tp, sk = tk * tk;
            #pragma unroll
            for (int m = 1; m < 32; m <<= 1) {
                sp += __shfl_xor(sp, m);
                sk += __shfl_xor(sk, m);
            }
            const float gate_prim = tanhf(o3[b][0]);
            const float gate_key  = tanhf(o3[b][1]);
            edc[hf][b] = sigmoidf_(decay_logit[n] + o3[b][2]);
            ep[hf][b]  = primitives[n * D + d] + mlr * gate_prim * (tp / fmaxf(sqrtf(sp), 1e-8f));
            ek_s[sub][hf][b][d] = key_w[n * D + d] + mlr * gate_key * (tk / fmaxf(sqrtf(sk), 1e-8f));
        }
    }
    __syncthreads();

    // routing: lane k=d handles conn[n,k] for both halves/batches
    #pragma unroll
    for (int hf = 0; hf < HALVES; ++hf) {
        const int n = gid + hf * (N / 2);
        const int k = d;
        const int j = conn[n * K + k];
        jl[sub][hf][k] = j;
        #pragma unroll
        for (int b = 0; b < 2; ++b) {
            const float4* pm = reinterpret_cast<const float4*>(
                prev_msgs + ((size_t)b * N + j) * D);
            float s = 0.f;
            #pragma unroll
            for (int q = 0; q < 8; ++q) {
                const float4 v = pm[q];
                s += ek_s[sub][hf][b][q*4+0] * v.x + ek_s[sub][hf][b][q*4+1] * v.y +
                     ek_s[sub][hf][b][q*4+2] * v.z + ek_s[sub][hf][b][q*4+3] * v.w;
            }
            rl[sub][hf][b][k] = sigmoidf_(s);
        }
    }

    // step-invariant per-thread state
    float breg[HALVES][32], gv[HALVES][4], hh[HALVES][2];
    #pragma unroll
    for (int hf = 0; hf < HALVES; ++hf) {
        const int n = gid + hf * (N / 2);
        const float* bwn = bw + (size_t)n * (K * D);
        #pragma unroll
        for (int k = 0; k < 32; ++k) breg[hf][k] = bwn[k * 32 + d];
        const float* gwn = gw + (size_t)n * 128;
        gv[hf][0] = gwn[d];      gv[hf][1] = gwn[32 + d];
        gv[hf][2] = gwn[64 + d]; gv[hf][3] = gwn[96 + d];
        hh[hf][0] = h_prev[(size_t)n * D + d];
        hh[hf][1] = h_prev[((size_t)N + n) * D + d];
    }
    __syncthreads();

    cg::grid_group grid = cg::this_grid();

    for (int s = 0; s < NT; ++s) {
        const float* msrc = (s == 0) ? prev_msgs : ((s & 1) ? m0buf : m1buf);
        float*       mdst = (s & 1) ? m1buf : m0buf;

        #pragma unroll
        for (int hf = 0; hf < HALVES; ++hf) {
            const int n = gid + hf * (N / 2);
            float bs0[4] = {0.f,0.f,0.f,0.f};
            float bs1[4] = {0.f,0.f,0.f,0.f};
            const int4*   jp  = reinterpret_cast<const int4*>(jl[sub][hf]);
            const float4* r0p = reinterpret_cast<const float4*>(rl[sub][hf][0]);
            const float4* r1p = reinterpret_cast<const float4*>(rl[sub][hf][1]);
            #pragma unroll
            for (int kk = 0; kk < 8; ++kk) {
                const int4   j4 = jp[kk];
                const float4 r0 = r0p[kk];
                const float4 r1 = r1p[kk];
                const int a = kk >> 1;
                { const float w = breg[hf][kk*4+0];
                  bs0[a] += r0.x * msrc[(size_t)j4.x * D + d] * w;
                  bs1[a] += r1.x * msrc[((size_t)N + j4.x) * D + d] * w; }
                { const float w = breg[hf][kk*4+1];
                  bs0[a] += r0.y * msrc[(size_t)j4.y * D + d] * w;
                  bs1[a] += r1.y * msrc[((size_t)N + j4.y) * D + d] * w; }
                { const float w = breg[hf][kk*4+2];
                  bs0[a] += r0.z * msrc[(size_t)j4.z * D + d] * w;
                  bs1[a] += r1.z * msrc[((size_t)N + j4.z) * D + d] * w; }
                { const float w = breg[hf][kk*4+3];
                  bs0[a] += r0.w * msrc[(size_t)j4.w * D + d] * w;
                  bs1[a] += r1.w * msrc[((size_t)N + j4.w) * D + d] * w; }
            }

            float rec0 = tanhf(tanhf(bs0[0])*gv[hf][0] + tanhf(bs0[1])*gv[hf][1] +
                               tanhf(bs0[2])*gv[hf][2] + tanhf(bs0[3])*gv[hf][3]);
            float rec1 = tanhf(tanhf(bs1[0])*gv[hf][0] + tanhf(bs1[1])*gv[hf][1] +
                               tanhf(bs1[2])*gv[hf][2] + tanhf(bs1[3])*gv[hf][3]);

            const size_t t0 = (size_t)(s * STRIDE) * (C * D) + (size_t)n * D + d;
            if (n < C) {
                rec0 += cc[t0];
                rec1 += cc[(size_t)(T * C * D) + t0];
            }

            hh[hf][0] = edc[hf][0] * hh[hf][0] + (1.f - edc[hf][0]) * rec0;
            hh[hf][1] = edc[hf][1] * hh[hf][1] + (1.f - edc[hf][1]) * rec1;
            const float msg0 = tanhf(hh[hf][0] * ep[hf][0]);
            const float msg1 = tanhf(hh[hf][1] * ep[hf][1]);
            mdst[(size_t)n * D + d]       = msg0;
            mdst[((size_t)N + n) * D + d] = msg1;

            if (n < C) {
                #pragma unroll
                for (int r = 0; r < STRIDE; ++r) {
                    out[t0 + (size_t)r * (C * D)] = msg0;
                    out[(size_t)(T * C * D) + t0 + (size_t)r * (C * D)] = msg1;
                }
            }
        }

        if (s < NT - 1) {
            __threadfence();
            grid.sync();
        }
    }
}

// ===========================================================================
// Fallback path (proven R2 structure), used only if cooperative launch fails.
// ===========================================================================
__global__ __launch_bounds__(256) void phase1_fb(
    const float* __restrict__ h_prev, const float* __restrict__ prev_msgs,
    const float* __restrict__ trace_prim, const float* __restrict__ trace_key,
    const float* __restrict__ primitives, const float* __restrict__ key_w,
    const float* __restrict__ decay_logit, const float* __restrict__ fc1_w,
    const float* __restrict__ fc1_b, const float* __restrict__ fc2_w,
    const float* __restrict__ fc2_b, const float* __restrict__ mod_lr_logit,
    const int* __restrict__ conn,
    float* __restrict__ ws_ed, float* __restrict__ ws_ep, float* __restrict__ ws_rt)
{
    const int n = blockIdx.x;
    const int t = threadIdx.x;

    __shared__ float mi[2][MOD_IN];
    __shared__ __align__(16) float red[2][16][64];
    __shared__ float ek[2][D];
    __shared__ float o3s[2][3];
    __shared__ int nzs;

    if (t == 0) nzs = 0;
    __syncthreads();
    if (t < 192) { if (fc2_w[(size_t)n * (H*3) + t] != 0.0f) atomicOr(&nzs, 1); }
    __syncthreads();
    const int nz = nzs;

    if (nz) {
        for (int idx = t; idx < 2 * MOD_IN; idx += 256) {
            const int b = idx / MOD_IN;
            const int d = idx - b * MOD_IN;
            float v;
            if (d < 32)        v = h_prev[(b * N + n) * D + d];
            else if (d < 64)   v = trace_prim[(b * N + n) * D + (d - 32)];
            else if (d < 96)   v = trace_key[(b * N + n) * D + (d - 64)];
            else if (d < 128)  v = primitives[n * D + (d - 96)];
            else               v = key_w[n * D + (d - 128)];
            mi[b][d] = v;
        }
        __syncthreads();
        {
            const int hq = t & 15;
            const int c  = t >> 4;
            const float* Wp = fc1_w + (size_t)n * (MOD_IN * H) + hq * 4;
            float a0x=0,a0y=0,a0z=0,a0w=0, a1x=0,a1y=0,a1z=0,a1w=0;
            #pragma unroll
            for (int j = 0; j < 10; ++j) {
                const int d = c * 10 + j;
                const float4 w = *reinterpret_cast<const float4*>(Wp + d * H);
                const float m0 = mi[0][d];
                const float m1 = mi[1][d];
                a0x += m0*w.x; a0y += m0*w.y; a0z += m0*w.z; a0w += m0*w.w;
                a1x += m1*w.x; a1y += m1*w.y; a1z += m1*w.z; a1w += m1*w.w;
            }
            *reinterpret_cast<float4*>(&red[0][c][hq*4]) = make_float4(a0x,a0y,a0z,a0w);
            *reinterpret_cast<float4*>(&red[1][c][hq*4]) = make_float4(a1x,a1y,a1z,a1w);
        }
        __syncthreads();
        if (t < 128) {
            const int b = t >> 6;
            const int h = t & 63;
            float s = 0.f;
            #pragma unroll
            for (int c2 = 0; c2 < 16; ++c2) s += red[b][c2][h];
            const float x = tanhf(s + fc1_b[n * H + h]);
            float o3[3];
            #pragma unroll
            for (int o = 0; o < 3; ++o) {
                float p = x * fc2_w[(size_t)n * (H*3) + h * 3 + o];
                #pragma unroll
                for (int m = 1; m < 64; m <<= 1) p += __shfl_xor(p, m, 64);
                o3[o] = p + fc2_b[n * 3 + o];
            }
            if (h == 0) { o3s[b][0]=o3[0]; o3s[b][1]=o3[1]; o3s[b][2]=o3[2]; }
        }
    } else {
        if (t < 6) {
            const int b = t / 3;
            const int o = t - b * 3;
            o3s[b][o] = fc2_b[n * 3 + o];
        }
    }
    __syncthreads();

    if (t < 128) {
        const int b = t >> 6;
        const int h = t & 63;
        const float mlr       = sigmoidf_(mod_lr_logit[0]);
        const float gate_prim = tanhf(o3s[b][0]);
        const float gate_key  = tanhf(o3s[b][1]);
        const float edv       = sigmoidf_(decay_logit[n] + o3s[b][2]);
        if (h == 0) ws_ed[b * N + n] = edv;

        const int d = h & 31;
        const float tp = trace_prim[(b * N + n) * D + d];
        const float tk = trace_key [(b * N + n) * D + d];
        float sp = tp * tp, sk = tk * tk;
        #pragma unroll
        for (int m = 1; m < 32; m <<= 1) {
            sp += __shfl_xor(sp, m);
            sk += __shfl_xor(sk, m);
        }
        const float epv = primitives[n*D+d] + mlr*gate_prim*(tp / fmaxf(sqrtf(sp), 1e-8f));
        const float ekv = key_w[n*D+d]      + mlr*gate_key *(tk / fmaxf(sqrtf(sk), 1e-8f));
        if (h < 32) {
            ws_ep[(size_t)(b * N + n) * D + d] = epv;
            ek[b][d] = ekv;
        }
    }
    __syncthreads();

    if (t < 64) {
        const int b = t >> 5;
        const int k = t & 31;
        const int j = conn[n * K + k];
        const float4* pm = reinterpret_cast<const float4*>(prev_msgs + (size_t)(b*N+j)*D);
        float s = 0.f;
        #pragma unroll
        for (int q = 0; q < 8; ++q) {
            const float4 v = pm[q];
            s += ek[b][q*4+0]*v.x + ek[b][q*4+1]*v.y + ek[b][q*4+2]*v.z + ek[b][q*4+3]*v.w;
        }
        ws_rt[(size_t)(b * N + n) * K + k] = sigmoidf_(s);
    }
}

__global__ __launch_bounds__(256) void step_kernel(
    const float* __restrict__ msg_prev, float* __restrict__ msg_out,
    const float* __restrict__ h_in, float* __restrict__ h_out,
    const float* __restrict__ ws_ed, const float* __restrict__ ws_ep,
    const float* __restrict__ ws_rt, const float* __restrict__ bw,
    const float* __restrict__ gw, const float* __restrict__ cc,
    const int* __restrict__ conn, float* __restrict__ out, int step)
{
    const int g = blockIdx.x * 256 + threadIdx.x;
    const int d = g & 31;
    const int n = g >> 5;

    const int*   cp  = conn + n * K;
    const float* bwn = bw + (size_t)n * 1024;
    const float* rt0 = ws_rt + (size_t)n * K;
    const float* rt1 = ws_rt + (size_t)(N + n) * K;
    const float* mp0 = msg_prev;
    const float* mp1 = msg_prev + (size_t)N * D;

    float bs0[4] = {0.f,0.f,0.f,0.f};
    float bs1[4] = {0.f,0.f,0.f,0.f};
    #pragma unroll
    for (int k = 0; k < 32; ++k) {
        const int j = cp[k];
        const float w = bwn[k * 32 + d];
        bs0[k >> 3] += rt0[k] * mp0[j * D + d] * w;
        bs1[k >> 3] += rt1[k] * mp1[j * D + d] * w;
    }

    const float* gwn = gw + (size_t)n * 128;
    const float g0 = gwn[d], g1 = gwn[32+d], g2 = gwn[64+d], g3 = gwn[96+d];

    #pragma unroll
    for (int b = 0; b < 2; ++b) {
        const float* bs = (b == 0) ? bs0 : bs1;
        float rec = tanhf(tanhf(bs[0])*g0 + tanhf(bs[1])*g1 +
                          tanhf(bs[2])*g2 + tanhf(bs[3])*g3);
        const size_t t0 = (size_t)b*(T*C*D) + (size_t)(step*STRIDE)*(C*D) + n*D + d;
        if (n < C) rec += cc[t0];
        const int pair = b * N + n;
        const float ed = ws_ed[pair];
        const float hn = ed * h_in[(size_t)pair*D + d] + (1.f - ed) * rec;
        h_out[(size_t)pair*D + d] = hn;
        const float msg = tanhf(hn * ws_ep[(size_t)pair*D + d]);
        msg_out[(size_t)pair*D + d] = msg;
        if (n < C) {
            #pragma unroll
            for (int r = 0; r < STRIDE; ++r) out[t0 + (size_t)r*(C*D)] = msg;
        }
    }
}

// ===========================================================================
extern "C" void kernel_launch(void* const* d_in, const int* in_sizes, int n_in,
                              void* d_out, int out_size, void* d_ws, size_t ws_size,
                              hipStream_t stream) {
    const float* cc          = (const float*)d_in[0];
    const float* h_prev      = (const float*)d_in[1];
    const float* prev_msgs   = (const float*)d_in[2];
    const float* trace_prim  = (const float*)d_in[3];
    const float* trace_key   = (const float*)d_in[4];
    const float* primitives  = (const float*)d_in[5];
    const float* key_w       = (const float*)d_in[6];
    const float* decay_logit = (const float*)d_in[7];
    const float* bw          = (const float*)d_in[8];
    const float* gw          = (const float*)d_in[9];
    const float* fc1_w       = (const float*)d_in[10];
    const float* fc1_b       = (const float*)d_in[11];
    const float* fc2_w       = (const float*)d_in[12];
    const float* fc2_b       = (const float*)d_in[13];
    const float* mod_lr      = (const float*)d_in[14];
    const int*   conn        = (const int*)d_in[15];
    // d_in[16] = stride (4, baked into STRIDE)

    float* m0    = (float*)d_ws;                 // BS*N*D
    float* m1    = m0 + (size_t)BS * N * D;      // BS*N*D
    float* ws_ed = m1 + (size_t)BS * N * D;      // BS*N
    float* ws_ep = ws_ed + BS * N;               // BS*N*D
    float* ws_rt = ws_ep + (size_t)BS * N * D;   // BS*N*K
    float* ws_h  = ws_rt + (size_t)BS * N * K;   // BS*N*D
    float* outp  = (float*)d_out;

    void* args[] = {
        (void*)&cc, (void*)&h_prev, (void*)&prev_msgs, (void*)&trace_prim,
        (void*)&trace_key, (void*)&primitives, (void*)&key_w, (void*)&decay_logit,
        (void*)&bw, (void*)&gw, (void*)&fc1_w, (void*)&fc1_b, (void*)&fc2_w,
        (void*)&fc2_b, (void*)&mod_lr, (void*)&conn,
        (void*)&m0, (void*)&m1, (void*)&outp
    };

    hipError_t err = hipLaunchCooperativeKernel((void*)fused_kernel, dim3(GRID),
                                                dim3(256), args, 0, stream);
    if (err != hipSuccess) {
        // Fallback: proven multi-dispatch path (identical math).
        phase1_fb<<<N, 256, 0, stream>>>(
            h_prev, prev_msgs, trace_prim, trace_key, primitives, key_w,
            decay_logit, fc1_w, fc1_b, fc2_w, fc2_b, mod_lr, conn,
            ws_ed, ws_ep, ws_rt);
        const int sb = (N * D) / 256;
        step_kernel<<<sb, 256, 0, stream>>>(prev_msgs, m0, h_prev, ws_h,
            ws_ed, ws_ep, ws_rt, bw, gw, cc, conn, outp, 0);
        step_kernel<<<sb, 256, 0, stream>>>(m0, m1, ws_h, ws_h,
            ws_ed, ws_ep, ws_rt, bw, gw, cc, conn, outp, 1);
        step_kernel<<<sb, 256, 0, stream>>>(m1, m0, ws_h, ws_h,
            ws_ed, ws_ep, ws_rt, bw, gw, cc, conn, outp, 2);
        step_kernel<<<sb, 256, 0, stream>>>(m0, m1, ws_h, ws_h,
            ws_ed, ws_ep, ws_rt, bw, gw, cc, conn, outp, 3);
    }
}

// Round 5
// 139.242 us; speedup vs baseline: 2.6354x; 2.6354x over previous
//
#include <hip/hip_runtime.h>

// Problem constants (MemoryGraph_15453292331249)
constexpr int N  = 8192;
constexpr int K  = 32;
constexpr int D  = 32;
constexpr int BS = 2;
constexpr int T  = 16;
constexpr int C  = 64;
constexpr int H  = 64;
constexpr int MOD_IN = 5 * D;   // 160
constexpr int STRIDE = 4;

__device__ __forceinline__ float sigmoidf_(float x) { return 1.0f / (1.0f + expf(-x)); }

// ===========================================================================
// Kernel A: per-neuron block (8192 x 256). zcheck -> o3 -> gates/ed/ep/ek ->
// routing (stashing neighbor rows in LDS) -> step 0 fused (gather is free).
// Writes packed-by-batch workspaces: ed[n][2], ep[(n*D+d)][2], rt[(n*K+k)][2],
// h[(n*D+d)][2], msg[(n*D+d)][2].
// ===========================================================================
__global__ __launch_bounds__(256) void phase1_step0_kernel(
    const float* __restrict__ cc,          // (BS,T,C,D)
    const float* __restrict__ h_prev,      // (BS,N,D)
    const float* __restrict__ prev_msgs,   // (BS,N,D)
    const float* __restrict__ trace_prim,  // (BS,N,D)
    const float* __restrict__ trace_key,   // (BS,N,D)
    const float* __restrict__ primitives,  // (N,D)
    const float* __restrict__ key_w,       // (N,D)
    const float* __restrict__ decay_logit, // (N,)
    const float* __restrict__ bw,          // (N,K,D)
    const float* __restrict__ gw,          // (N,4,32)
    const float* __restrict__ fc1_w,       // (N,160,64)
    const float* __restrict__ fc1_b,       // (N,64)
    const float* __restrict__ fc2_w,       // (N,64,3)
    const float* __restrict__ fc2_b,       // (N,3)
    const float* __restrict__ mod_lr_logit,// (1,)
    const int*   __restrict__ conn,        // (N,K)
    float* __restrict__ ws_ed,             // (N,2)
    float* __restrict__ ws_ep,             // (N*D,2)
    float* __restrict__ ws_rt,             // (N*K,2)
    float* __restrict__ ws_h,              // (N*D,2)
    float* __restrict__ ws_m,              // (N*D,2)  step-0 messages
    float* __restrict__ out)               // (BS,T,C,D)
{
    const int n = blockIdx.x;
    const int t = threadIdx.x;

    __shared__ float mi[2][MOD_IN];
    __shared__ __align__(16) float red[2][16][64];
    __shared__ float ek[2][D];
    __shared__ float o3s[2][3];
    __shared__ float rts[2][K];
    __shared__ float eps[2][D];
    __shared__ float eds[2];
    __shared__ float rows[2][K][D + 1];   // +1 pad: conflict-free stash/read
    __shared__ int nzs;

    // ---- per-neuron fc2_w zero-check (skip-multiply-by-zero, data-driven)
    if (t == 0) nzs = 0;
    __syncthreads();
    if (t < 192) { if (fc2_w[(size_t)n * (H * 3) + t] != 0.0f) atomicOr(&nzs, 1); }
    __syncthreads();
    const int nz = nzs;

    if (nz) {
        // General path: full fc1 matvec + fc2 (correct for arbitrary inputs)
        for (int idx = t; idx < 2 * MOD_IN; idx += 256) {
            const int b = idx / MOD_IN;
            const int d = idx - b * MOD_IN;
            float v;
            if (d < 32)        v = h_prev[(b * N + n) * D + d];
            else if (d < 64)   v = trace_prim[(b * N + n) * D + (d - 32)];
            else if (d < 96)   v = trace_key[(b * N + n) * D + (d - 64)];
            else if (d < 128)  v = primitives[n * D + (d - 96)];
            else               v = key_w[n * D + (d - 128)];
            mi[b][d] = v;
        }
        __syncthreads();
        {
            const int hq = t & 15;
            const int c  = t >> 4;
            const float* Wp = fc1_w + (size_t)n * (MOD_IN * H) + hq * 4;
            float a0x=0,a0y=0,a0z=0,a0w=0, a1x=0,a1y=0,a1z=0,a1w=0;
            #pragma unroll
            for (int j = 0; j < 10; ++j) {
                const int d = c * 10 + j;
                const float4 w = *reinterpret_cast<const float4*>(Wp + d * H);
                const float m0 = mi[0][d];
                const float m1 = mi[1][d];
                a0x += m0*w.x; a0y += m0*w.y; a0z += m0*w.z; a0w += m0*w.w;
                a1x += m1*w.x; a1y += m1*w.y; a1z += m1*w.z; a1w += m1*w.w;
            }
            *reinterpret_cast<float4*>(&red[0][c][hq*4]) = make_float4(a0x,a0y,a0z,a0w);
            *reinterpret_cast<float4*>(&red[1][c][hq*4]) = make_float4(a1x,a1y,a1z,a1w);
        }
        __syncthreads();
        if (t < 128) {
            const int b = t >> 6;
            const int h = t & 63;
            float s = 0.f;
            #pragma unroll
            for (int c2 = 0; c2 < 16; ++c2) s += red[b][c2][h];
            const float x = tanhf(s + fc1_b[n * H + h]);
            float o3[3];
            #pragma unroll
            for (int o = 0; o < 3; ++o) {
                float p = x * fc2_w[(size_t)n * (H*3) + h * 3 + o];
                #pragma unroll
                for (int m = 1; m < 64; m <<= 1) p += __shfl_xor(p, m, 64);
                o3[o] = p + fc2_b[n * 3 + o];
            }
            if (h == 0) { o3s[b][0]=o3[0]; o3s[b][1]=o3[1]; o3s[b][2]=o3[2]; }
        }
    } else {
        // fc2_w slice == 0  =>  o3 = fc2_b (x irrelevant; fc1 skipped)
        if (t < 6) {
            const int b = t / 3;
            const int o = t - b * 3;
            o3s[b][o] = fc2_b[n * 3 + o];
        }
    }
    __syncthreads();

    // ---- gates, eff_decay, eff_prim, eff_key
    if (t < 128) {
        const int b = t >> 6;
        const int h = t & 63;
        const float mlr       = sigmoidf_(mod_lr_logit[0]);
        const float gate_prim = tanhf(o3s[b][0]);
        const float gate_key  = tanhf(o3s[b][1]);
        const float edv       = sigmoidf_(decay_logit[n] + o3s[b][2]);
        if (h == 0) { ws_ed[n * 2 + b] = edv; eds[b] = edv; }

        const int d = h & 31;
        const float tp = trace_prim[(b * N + n) * D + d];
        const float tk = trace_key [(b * N + n) * D + d];
        float sp = tp * tp, sk = tk * tk;
        #pragma unroll
        for (int m = 1; m < 32; m <<= 1) {
            sp += __shfl_xor(sp, m);
            sk += __shfl_xor(sk, m);
        }
        const float epv = primitives[n*D+d] + mlr*gate_prim*(tp / fmaxf(sqrtf(sp), 1e-8f));
        const float ekv = key_w[n*D+d]      + mlr*gate_key *(tk / fmaxf(sqrtf(sk), 1e-8f));
        if (h < 32) {
            ws_ep[((size_t)n * D + d) * 2 + b] = epv;
            eps[b][d] = epv;
            ek[b][d]  = ekv;
        }
    }
    __syncthreads();

    // ---- routing + neighbor-row stash (rows reused by fused step 0)
    if (t < 64) {
        const int b = t >> 5;
        const int k = t & 31;
        const int j = conn[n * K + k];
        const float4* pm = reinterpret_cast<const float4*>(prev_msgs + (size_t)(b*N+j)*D);
        float s = 0.f;
        #pragma unroll
        for (int q = 0; q < 8; ++q) {
            const float4 v = pm[q];
            s += ek[b][q*4+0]*v.x + ek[b][q*4+1]*v.y + ek[b][q*4+2]*v.z + ek[b][q*4+3]*v.w;
            rows[b][k][q*4+0] = v.x; rows[b][k][q*4+1] = v.y;
            rows[b][k][q*4+2] = v.z; rows[b][k][q*4+3] = v.w;
        }
        const float rtv = sigmoidf_(s);
        ws_rt[((size_t)n * K + k) * 2 + b] = rtv;
        rts[b][k] = rtv;
    }
    __syncthreads();

    // ---- fused step 0 (gather already in LDS)
    if (t < 64) {
        const int b = t >> 5;
        const int d = t & 31;
        const float* bwn = bw + (size_t)n * (K * D);
        float bs[4] = {0.f, 0.f, 0.f, 0.f};
        #pragma unroll
        for (int k = 0; k < 32; ++k) {
            const float w = __builtin_nontemporal_load(bwn + k * 32 + d);
            bs[k >> 3] += rts[b][k] * rows[b][k][d] * w;
        }
        const float* gwn = gw + (size_t)n * 128;
        float rec = tanhf(tanhf(bs[0])*gwn[d] + tanhf(bs[1])*gwn[32+d] +
                          tanhf(bs[2])*gwn[64+d] + tanhf(bs[3])*gwn[96+d]);
        const size_t t0 = (size_t)n * D + d;                 // time index 0
        if (n < C) rec += cc[(size_t)b * (T*C*D) + t0];
        const float ed = eds[b];
        const float hn = ed * h_prev[((size_t)b*N + n)*D + d] + (1.f - ed) * rec;
        const float msg = tanhf(hn * eps[b][d]);
        ws_h[t0 * 2 + b] = hn;
        ws_m[t0 * 2 + b] = msg;
        if (n < C) {
            #pragma unroll
            for (int r = 0; r < STRIDE; ++r)
                out[(size_t)b*(T*C*D) + t0 + (size_t)r*(C*D)] = msg;
        }
    }
}

// ===========================================================================
// Kernel B: one scan step (1..3). Thread owns (n,d), both batches via packed
// float2 workspaces. Separate dispatch = global barrier + warm per-XCD L2.
// ===========================================================================
__global__ __launch_bounds__(256, 4) void step_kernel(
    const float2* __restrict__ msrc,   // (N*D) packed msgs
    float2*       __restrict__ mdst,   // (N*D)
    float2*       __restrict__ ws_h,   // (N*D) in/out
    const float2* __restrict__ ws_ed,  // (N)
    const float2* __restrict__ ws_ep,  // (N*D)
    const float*  __restrict__ ws_rt,  // (N*K,2)
    const float*  __restrict__ bw,     // (N,K,D)
    const float*  __restrict__ gw,     // (N,4,32)
    const float*  __restrict__ cc,     // (BS,T,C,D)
    const int*    __restrict__ conn,   // (N,K)
    float*        __restrict__ out,    // (BS,T,C,D)
    int step)
{
    const int g = blockIdx.x * 256 + threadIdx.x;  // over N*D
    const int d = g & 31;
    const int n = g >> 5;

    const int4*   jp  = reinterpret_cast<const int4*>(conn + n * K);
    const float4* rp  = reinterpret_cast<const float4*>(ws_rt + (size_t)n * K * 2);
    const float*  bwn = bw + (size_t)n * (K * D);

    float bs0[4] = {0.f,0.f,0.f,0.f};
    float bs1[4] = {0.f,0.f,0.f,0.f};
    #pragma unroll
    for (int kk = 0; kk < 8; ++kk) {     // 4 k's per iteration
        const int4   j4 = jp[kk];
        const float4 ra = rp[2*kk];      // rt pairs k=4kk, 4kk+1
        const float4 rb = rp[2*kk+1];    // rt pairs k=4kk+2, 4kk+3
        const float w0 = __builtin_nontemporal_load(bwn + (4*kk+0)*32 + d);
        const float w1 = __builtin_nontemporal_load(bwn + (4*kk+1)*32 + d);
        const float w2 = __builtin_nontemporal_load(bwn + (4*kk+2)*32 + d);
        const float w3 = __builtin_nontemporal_load(bwn + (4*kk+3)*32 + d);
        const float2 m0 = msrc[(size_t)j4.x * D + d];
        const float2 m1 = msrc[(size_t)j4.y * D + d];
        const float2 m2 = msrc[(size_t)j4.z * D + d];
        const float2 m3 = msrc[(size_t)j4.w * D + d];
        const int a = kk >> 1;
        bs0[a] += ra.x * m0.x * w0;  bs1[a] += ra.y * m0.y * w0;
        bs0[a] += ra.z * m1.x * w1;  bs1[a] += ra.w * m1.y * w1;
        bs0[a] += rb.x * m2.x * w2;  bs1[a] += rb.y * m2.y * w2;
        bs0[a] += rb.z * m3.x * w3;  bs1[a] += rb.w * m3.y * w3;
    }

    const float* gwn = gw + (size_t)n * 128;
    const float g0 = gwn[d], g1 = gwn[32+d], g2 = gwn[64+d], g3 = gwn[96+d];

    float rec0 = tanhf(tanhf(bs0[0])*g0 + tanhf(bs0[1])*g1 +
                       tanhf(bs0[2])*g2 + tanhf(bs0[3])*g3);
    float rec1 = tanhf(tanhf(bs1[0])*g0 + tanhf(bs1[1])*g1 +
                       tanhf(bs1[2])*g2 + tanhf(bs1[3])*g3);

    const size_t idx = (size_t)n * D + d;
    const size_t t0  = (size_t)(step * STRIDE) * (C * D) + idx;
    if (n < C) {
        rec0 += cc[t0];
        rec1 += cc[(size_t)(T * C * D) + t0];
    }

    const float2 ed2 = ws_ed[n];
    const float2 h2  = ws_h[idx];
    const float2 ep2 = ws_ep[idx];
    float2 hn, mg;
    hn.x = ed2.x * h2.x + (1.f - ed2.x) * rec0;
    hn.y = ed2.y * h2.y + (1.f - ed2.y) * rec1;
    mg.x = tanhf(hn.x * ep2.x);
    mg.y = tanhf(hn.y * ep2.y);
    ws_h[idx] = hn;
    mdst[idx] = mg;

    if (n < C) {
        #pragma unroll
        for (int r = 0; r < STRIDE; ++r) {
            out[t0 + (size_t)r * (C * D)] = mg.x;
            out[(size_t)(T * C * D) + t0 + (size_t)r * (C * D)] = mg.y;
        }
    }
}

// ===========================================================================
extern "C" void kernel_launch(void* const* d_in, const int* in_sizes, int n_in,
                              void* d_out, int out_size, void* d_ws, size_t ws_size,
                              hipStream_t stream) {
    const float* cc          = (const float*)d_in[0];
    const float* h_prev      = (const float*)d_in[1];
    const float* prev_msgs   = (const float*)d_in[2];
    const float* trace_prim  = (const float*)d_in[3];
    const float* trace_key   = (const float*)d_in[4];
    const float* primitives  = (const float*)d_in[5];
    const float* key_w       = (const float*)d_in[6];
    const float* decay_logit = (const float*)d_in[7];
    const float* bw          = (const float*)d_in[8];
    const float* gw          = (const float*)d_in[9];
    const float* fc1_w       = (const float*)d_in[10];
    const float* fc1_b       = (const float*)d_in[11];
    const float* fc2_w       = (const float*)d_in[12];
    const float* fc2_b       = (const float*)d_in[13];
    const float* mod_lr      = (const float*)d_in[14];
    const int*   conn        = (const int*)d_in[15];
    // d_in[16] = stride (4, baked into STRIDE)

    float* ws    = (float*)d_ws;
    float* ws_ma = ws;                            // N*D*2
    float* ws_mb = ws_ma + (size_t)N * D * 2;     // N*D*2
    float* ws_h  = ws_mb + (size_t)N * D * 2;     // N*D*2
    float* ws_ed = ws_h  + (size_t)N * D * 2;     // N*2
    float* ws_ep = ws_ed + (size_t)N * 2;         // N*D*2
    float* ws_rt = ws_ep + (size_t)N * D * 2;     // N*K*2
    float* outp  = (float*)d_out;

    phase1_step0_kernel<<<N, 256, 0, stream>>>(
        cc, h_prev, prev_msgs, trace_prim, trace_key, primitives, key_w,
        decay_logit, bw, gw, fc1_w, fc1_b, fc2_w, fc2_b, mod_lr, conn,
        ws_ed, ws_ep, ws_rt, ws_h, ws_ma, outp);

    const int sb = (N * D) / 256;  // 1024 blocks
    step_kernel<<<sb, 256, 0, stream>>>((const float2*)ws_ma, (float2*)ws_mb,
        (float2*)ws_h, (const float2*)ws_ed, (const float2*)ws_ep, ws_rt,
        bw, gw, cc, conn, outp, 1);
    step_kernel<<<sb, 256, 0, stream>>>((const float2*)ws_mb, (float2*)ws_ma,
        (float2*)ws_h, (const float2*)ws_ed, (const float2*)ws_ep, ws_rt,
        bw, gw, cc, conn, outp, 2);
    step_kernel<<<sb, 256, 0, stream>>>((const float2*)ws_ma, (float2*)ws_mb,
        (float2*)ws_h, (const float2*)ws_ed, (const float2*)ws_ep, ws_rt,
        bw, gw, cc, conn, outp, 3);
}

// Round 6
// 81.924 us; speedup vs baseline: 4.4792x; 1.6997x over previous
//
#include <hip/hip_runtime.h>

// Problem constants (MemoryGraph_15453292331249)
constexpr int N  = 8192;
constexpr int K  = 32;
constexpr int D  = 32;
constexpr int BS = 2;
constexpr int T  = 16;
constexpr int C  = 64;
constexpr int H  = 64;
constexpr int MOD_IN = 5 * D;   // 160
constexpr int STRIDE = 4;
constexpr int NPB = 8;          // neurons (32-lane groups) per block

__device__ __forceinline__ float sigmoidf_(float x) { return 1.0f / (1.0f + expf(-x)); }

// ===========================================================================
// Phase 1: 1024 blocks x 256 threads; 32-lane group owns one neuron; all
// lanes active. zcheck (shfl-OR) -> o3 (fast path o3=fc2_b when fc2_w slice
// is all-zero, data-driven; else full fc1 matvec) -> gates/ed/ep/ek ->
// routing. Writes R2-layout workspaces.
// ===========================================================================
__global__ __launch_bounds__(256) void phase1_kernel(
    const float* __restrict__ h_prev,      // (BS,N,D)
    const float* __restrict__ prev_msgs,   // (BS,N,D)
    const float* __restrict__ trace_prim,  // (BS,N,D)
    const float* __restrict__ trace_key,   // (BS,N,D)
    const float* __restrict__ primitives,  // (N,D)
    const float* __restrict__ key_w,       // (N,D)
    const float* __restrict__ decay_logit, // (N,)
    const float* __restrict__ fc1_w,       // (N,160,64)
    const float* __restrict__ fc1_b,       // (N,64)
    const float* __restrict__ fc2_w,       // (N,64,3)
    const float* __restrict__ fc2_b,       // (N,3)
    const float* __restrict__ mod_lr_logit,// (1,)
    const int*   __restrict__ conn,        // (N,K)
    float* __restrict__ ws_ed,             // (BS,N)
    float* __restrict__ ws_ep,             // (BS,N,D)
    float* __restrict__ ws_rt)             // (BS,N,K)
{
    const int t   = threadIdx.x;
    const int sub = t >> 5;
    const int d   = t & 31;
    const int n   = blockIdx.x * NPB + sub;

    __shared__ __align__(16) float ek_s[NPB][2][D];

    // ---- per-neuron fc2_w slice zero-check (skip multiply-by-zero; data-driven)
    const float* f2w = fc2_w + n * (H * 3);
    int nzf = 0;
    #pragma unroll
    for (int i = 0; i < 6; ++i) nzf |= (f2w[i * 32 + d] != 0.0f);
    #pragma unroll
    for (int m = 1; m < 32; m <<= 1) nzf |= __shfl_xor(nzf, m);

    float o3[2][3];
    if (!nzf) {
        #pragma unroll
        for (int o = 0; o < 3; ++o) {
            const float v = fc2_b[n * 3 + o];
            o3[0][o] = v; o3[1][o] = v;
        }
    } else {
        // General path: full fc1 matvec + fc2 (lane computes h=d and h=d+32).
        const float* W = fc1_w + (size_t)n * (MOD_IN * H);
        #pragma unroll
        for (int b = 0; b < 2; ++b) {
            const size_t base = ((size_t)b * N + n) * D + d;
            float mv[5];
            mv[0] = h_prev[base];
            mv[1] = trace_prim[base];
            mv[2] = trace_key[base];
            mv[3] = primitives[n * D + d];
            mv[4] = key_w[n * D + d];
            float acc0 = 0.f, acc1 = 0.f;
            #pragma unroll
            for (int c = 0; c < 5; ++c) {
                const float mc = mv[c];
                for (int dp = 0; dp < 32; ++dp) {
                    const float v = __shfl(mc, dp, 32);
                    const float* wr = W + (c * 32 + dp) * H;
                    acc0 += v * wr[d];
                    acc1 += v * wr[d + 32];
                }
            }
            const float x0 = tanhf(acc0 + fc1_b[n * H + d]);
            const float x1 = tanhf(acc1 + fc1_b[n * H + d + 32]);
            #pragma unroll
            for (int o = 0; o < 3; ++o) {
                float p = x0 * f2w[d * 3 + o] + x1 * f2w[(d + 32) * 3 + o];
                #pragma unroll
                for (int m = 1; m < 32; m <<= 1) p += __shfl_xor(p, m);
                o3[b][o] = p + fc2_b[n * 3 + o];
            }
        }
    }

    // ---- gates, eff_decay, eff_prim, eff_key
    const float mlr = sigmoidf_(mod_lr_logit[0]);
    #pragma unroll
    for (int b = 0; b < 2; ++b) {
        const size_t base = ((size_t)b * N + n) * D + d;
        const float tp = trace_prim[base];
        const float tk = trace_key[base];
        float sp = tp * tp, sk = tk * tk;
        #pragma unroll
        for (int m = 1; m < 32; m <<= 1) {
            sp += __shfl_xor(sp, m);
            sk += __shfl_xor(sk, m);
        }
        const float gate_prim = tanhf(o3[b][0]);
        const float gate_key  = tanhf(o3[b][1]);
        const float edv       = sigmoidf_(decay_logit[n] + o3[b][2]);
        if (d == 0) ws_ed[b * N + n] = edv;
        const float epv = primitives[n*D+d] + mlr*gate_prim*(tp / fmaxf(sqrtf(sp), 1e-8f));
        const float ekv = key_w[n*D+d]      + mlr*gate_key *(tk / fmaxf(sqrtf(sk), 1e-8f));
        ws_ep[base] = epv;
        ek_s[sub][b][d] = ekv;
    }
    __syncthreads();

    // ---- routing: lane k = d; rt = sigmoid(eff_key . prev_msgs[b, conn[n,k], :])
    {
        const int k = d;
        const int j = conn[n * K + k];
        #pragma unroll
        for (int b = 0; b < 2; ++b) {
            const float4* pm = reinterpret_cast<const float4*>(
                prev_msgs + ((size_t)b * N + j) * D);
            float s = 0.f;
            #pragma unroll
            for (int q = 0; q < 8; ++q) {
                const float4 v = pm[q];
                s += ek_s[sub][b][q*4+0] * v.x + ek_s[sub][b][q*4+1] * v.y +
                     ek_s[sub][b][q*4+2] * v.z + ek_s[sub][b][q*4+3] * v.w;
            }
            ws_rt[((size_t)b * N + n) * K + k] = sigmoidf_(s);
        }
    }
}

// ===========================================================================
// Phase 2: one scan step — VERBATIM the proven R2 step_kernel.
// Thread owns (n,d), processes both batches. Separate dispatch = barrier.
// ===========================================================================
__global__ __launch_bounds__(256) void step_kernel(
    const float* __restrict__ msg_prev,  // (BS,N,D)
    float*       __restrict__ msg_out,   // (BS,N,D)
    const float* __restrict__ h_in,      // (BS,N,D)
    float*       __restrict__ h_out,     // (BS,N,D)
    const float* __restrict__ ws_ed,     // (BS,N)
    const float* __restrict__ ws_ep,     // (BS,N,D)
    const float* __restrict__ ws_rt,     // (BS,N,K)
    const float* __restrict__ bw,        // (N,1024)
    const float* __restrict__ gw,        // (N,128)
    const float* __restrict__ cc,        // (BS,T,C,D)
    const int*   __restrict__ conn,      // (N,K)
    float*       __restrict__ out,       // (BS,T,C,D)
    int step)
{
    const int g = blockIdx.x * 256 + threadIdx.x;  // over N*D
    const int d = g & 31;
    const int n = g >> 5;

    const int*   cp  = conn + n * K;
    const float* bwn = bw + (size_t)n * 1024;
    const float* rt0 = ws_rt + (size_t)n * K;
    const float* rt1 = ws_rt + (size_t)(N + n) * K;
    const float* mp0 = msg_prev;
    const float* mp1 = msg_prev + (size_t)N * D;

    float bs0[4] = {0.f, 0.f, 0.f, 0.f};
    float bs1[4] = {0.f, 0.f, 0.f, 0.f};
    #pragma unroll
    for (int k = 0; k < 32; ++k) {
        const int j = cp[k];
        const float w = bwn[k * 32 + d];
        bs0[k >> 3] += rt0[k] * mp0[j * D + d] * w;
        bs1[k >> 3] += rt1[k] * mp1[j * D + d] * w;
    }

    const float* gwn = gw + (size_t)n * 128;
    const float g0 = gwn[d], g1 = gwn[32 + d], g2 = gwn[64 + d], g3 = gwn[96 + d];

    #pragma unroll
    for (int b = 0; b < 2; ++b) {
        const float* bs = (b == 0) ? bs0 : bs1;
        float gsum = tanhf(bs[0]) * g0 + tanhf(bs[1]) * g1 +
                     tanhf(bs[2]) * g2 + tanhf(bs[3]) * g3;
        float received = tanhf(gsum);

        const size_t tslot = (size_t)b * (T * C * D) +
                             (size_t)(step * STRIDE) * (C * D) + n * D + d;
        if (n < C) received += cc[tslot];

        const int pair = b * N + n;
        const float ed = ws_ed[pair];
        const float h  = h_in[(size_t)pair * D + d];
        const float hn = ed * h + (1.f - ed) * received;
        h_out[(size_t)pair * D + d] = hn;

        const float msg = tanhf(hn * ws_ep[(size_t)pair * D + d]);
        msg_out[(size_t)pair * D + d] = msg;

        if (n < C) {
            #pragma unroll
            for (int r = 0; r < STRIDE; ++r) out[tslot + (size_t)r * (C * D)] = msg;
        }
    }
}

// ===========================================================================
extern "C" void kernel_launch(void* const* d_in, const int* in_sizes, int n_in,
                              void* d_out, int out_size, void* d_ws, size_t ws_size,
                              hipStream_t stream) {
    const float* cc          = (const float*)d_in[0];
    const float* h_prev      = (const float*)d_in[1];
    const float* prev_msgs   = (const float*)d_in[2];
    const float* trace_prim  = (const float*)d_in[3];
    const float* trace_key   = (const float*)d_in[4];
    const float* primitives  = (const float*)d_in[5];
    const float* key_w       = (const float*)d_in[6];
    const float* decay_logit = (const float*)d_in[7];
    const float* bw          = (const float*)d_in[8];
    const float* gw          = (const float*)d_in[9];
    const float* fc1_w       = (const float*)d_in[10];
    const float* fc1_b       = (const float*)d_in[11];
    const float* fc2_w       = (const float*)d_in[12];
    const float* fc2_b       = (const float*)d_in[13];
    const float* mod_lr      = (const float*)d_in[14];
    const int*   conn        = (const int*)d_in[15];
    // d_in[16] = stride (4, baked into STRIDE)

    float* ws     = (float*)d_ws;
    float* ws_ed  = ws;                       // BS*N
    float* ws_ep  = ws_ed + BS * N;           // BS*N*D
    float* ws_rt  = ws_ep + BS * N * D;       // BS*N*K
    float* ws_h   = ws_rt + BS * N * K;       // BS*N*D
    float* ws_m0  = ws_h  + BS * N * D;       // BS*N*D
    float* ws_m1  = ws_m0 + BS * N * D;       // BS*N*D
    float* outp   = (float*)d_out;

    phase1_kernel<<<N / NPB, 256, 0, stream>>>(
        h_prev, prev_msgs, trace_prim, trace_key, primitives, key_w,
        decay_logit, fc1_w, fc1_b, fc2_w, fc2_b, mod_lr, conn,
        ws_ed, ws_ep, ws_rt);

    const int sb = (N * D) / 256;  // 1024 blocks
    step_kernel<<<sb, 256, 0, stream>>>(prev_msgs, ws_m0, h_prev, ws_h,
        ws_ed, ws_ep, ws_rt, bw, gw, cc, conn, outp, 0);
    step_kernel<<<sb, 256, 0, stream>>>(ws_m0, ws_m1, ws_h, ws_h,
        ws_ed, ws_ep, ws_rt, bw, gw, cc, conn, outp, 1);
    step_kernel<<<sb, 256, 0, stream>>>(ws_m1, ws_m0, ws_h, ws_h,
        ws_ed, ws_ep, ws_rt, bw, gw, cc, conn, outp, 2);
    step_kernel<<<sb, 256, 0, stream>>>(ws_m0, ws_m1, ws_h, ws_h,
        ws_ed, ws_ep, ws_rt, bw, gw, cc, conn, outp, 3);
}

// Round 7
// 73.599 us; speedup vs baseline: 4.9858x; 1.1131x over previous
//
#include <hip/hip_runtime.h>

// Problem constants (MemoryGraph_15453292331249)
constexpr int N  = 8192;
constexpr int K  = 32;
constexpr int D  = 32;
constexpr int BS = 2;
constexpr int T  = 16;
constexpr int C  = 64;
constexpr int H  = 64;
constexpr int MOD_IN = 5 * D;   // 160
constexpr int STRIDE = 4;
constexpr int NPB = 8;          // neurons (32-lane groups) per block

__device__ __forceinline__ float sigmoidf_(float x) { return 1.0f / (1.0f + expf(-x)); }

// ===========================================================================
// Phase 1: 1024 blocks x 256 threads; 32-lane group owns one neuron.
// zcheck -> o3 (fast path when fc2_w slice all-zero; else full fc1 matvec)
// -> gates/ed/ep/ek -> routing -> bw/gw per-neuron uniformity check
// (enables skip-the-weight-load fast path in steps; data-driven, general).
// ===========================================================================
__global__ __launch_bounds__(256) void phase1_kernel(
    const float* __restrict__ h_prev,      // (BS,N,D)
    const float* __restrict__ prev_msgs,   // (BS,N,D)
    const float* __restrict__ trace_prim,  // (BS,N,D)
    const float* __restrict__ trace_key,   // (BS,N,D)
    const float* __restrict__ primitives,  // (N,D)
    const float* __restrict__ key_w,       // (N,D)
    const float* __restrict__ decay_logit, // (N,)
    const float* __restrict__ bw,          // (N,K,D)
    const float* __restrict__ gw,          // (N,4,32)
    const float* __restrict__ fc1_w,       // (N,160,64)
    const float* __restrict__ fc1_b,       // (N,64)
    const float* __restrict__ fc2_w,       // (N,64,3)
    const float* __restrict__ fc2_b,       // (N,3)
    const float* __restrict__ mod_lr_logit,// (1,)
    const int*   __restrict__ conn,        // (N,K)
    float*  __restrict__ ws_ed,            // (BS,N)
    float*  __restrict__ ws_ep,            // (BS,N,D)
    float*  __restrict__ ws_rt,            // (BS,N,K)
    float4* __restrict__ ws_u)             // (N) {bw_uni, w0, gw_uni, g0}
{
    const int t   = threadIdx.x;
    const int sub = t >> 5;
    const int d   = t & 31;
    const int n   = blockIdx.x * NPB + sub;

    __shared__ __align__(16) float ek_s[NPB][2][D];

    // ---- per-neuron fc2_w slice zero-check (skip multiply-by-zero; data-driven)
    const float* f2w = fc2_w + n * (H * 3);
    int nzf = 0;
    #pragma unroll
    for (int i = 0; i < 6; ++i) nzf |= (f2w[i * 32 + d] != 0.0f);
    #pragma unroll
    for (int m = 1; m < 32; m <<= 1) nzf |= __shfl_xor(nzf, m);

    float o3[2][3];
    if (!nzf) {
        #pragma unroll
        for (int o = 0; o < 3; ++o) {
            const float v = fc2_b[n * 3 + o];
            o3[0][o] = v; o3[1][o] = v;
        }
    } else {
        // General path: full fc1 matvec + fc2 (lane computes h=d and h=d+32).
        const float* W = fc1_w + (size_t)n * (MOD_IN * H);
        #pragma unroll
        for (int b = 0; b < 2; ++b) {
            const size_t base = ((size_t)b * N + n) * D + d;
            float mv[5];
            mv[0] = h_prev[base];
            mv[1] = trace_prim[base];
            mv[2] = trace_key[base];
            mv[3] = primitives[n * D + d];
            mv[4] = key_w[n * D + d];
            float acc0 = 0.f, acc1 = 0.f;
            #pragma unroll
            for (int c = 0; c < 5; ++c) {
                const float mc = mv[c];
                for (int dp = 0; dp < 32; ++dp) {
                    const float v = __shfl(mc, dp, 32);
                    const float* wr = W + (c * 32 + dp) * H;
                    acc0 += v * wr[d];
                    acc1 += v * wr[d + 32];
                }
            }
            const float x0 = tanhf(acc0 + fc1_b[n * H + d]);
            const float x1 = tanhf(acc1 + fc1_b[n * H + d + 32]);
            #pragma unroll
            for (int o = 0; o < 3; ++o) {
                float p = x0 * f2w[d * 3 + o] + x1 * f2w[(d + 32) * 3 + o];
                #pragma unroll
                for (int m = 1; m < 32; m <<= 1) p += __shfl_xor(p, m);
                o3[b][o] = p + fc2_b[n * 3 + o];
            }
        }
    }

    // ---- gates, eff_decay, eff_prim, eff_key
    const float mlr = sigmoidf_(mod_lr_logit[0]);
    #pragma unroll
    for (int b = 0; b < 2; ++b) {
        const size_t base = ((size_t)b * N + n) * D + d;
        const float tp = trace_prim[base];
        const float tk = trace_key[base];
        float sp = tp * tp, sk = tk * tk;
        #pragma unroll
        for (int m = 1; m < 32; m <<= 1) {
            sp += __shfl_xor(sp, m);
            sk += __shfl_xor(sk, m);
        }
        const float gate_prim = tanhf(o3[b][0]);
        const float gate_key  = tanhf(o3[b][1]);
        const float edv       = sigmoidf_(decay_logit[n] + o3[b][2]);
        if (d == 0) ws_ed[b * N + n] = edv;
        const float epv = primitives[n*D+d] + mlr*gate_prim*(tp / fmaxf(sqrtf(sp), 1e-8f));
        const float ekv = key_w[n*D+d]      + mlr*gate_key *(tk / fmaxf(sqrtf(sk), 1e-8f));
        ws_ep[base] = epv;
        ek_s[sub][b][d] = ekv;
    }
    __syncthreads();

    // ---- routing: lane k = d; rt = sigmoid(eff_key . prev_msgs[b, conn[n,k], :])
    {
        const int k = d;
        const int j = conn[n * K + k];
        #pragma unroll
        for (int b = 0; b < 2; ++b) {
            const float4* pm = reinterpret_cast<const float4*>(
                prev_msgs + ((size_t)b * N + j) * D);
            float s = 0.f;
            #pragma unroll
            for (int q = 0; q < 8; ++q) {
                const float4 v = pm[q];
                s += ek_s[sub][b][q*4+0] * v.x + ek_s[sub][b][q*4+1] * v.y +
                     ek_s[sub][b][q*4+2] * v.z + ek_s[sub][b][q*4+3] * v.w;
            }
            ws_rt[((size_t)b * N + n) * K + k] = sigmoidf_(s);
        }
    }

    // ---- bw/gw per-neuron uniformity check (coalesced; lane-AND reduce)
    {
        const float* bwn = bw + (size_t)n * (K * D);
        const float b0 = bwn[0];
        int eqb = 1;
        #pragma unroll
        for (int k = 0; k < 32; ++k) eqb &= (bwn[k * 32 + d] == b0);
        const float* gwn = gw + (size_t)n * 128;
        const float g0 = gwn[0];
        int eqg = (gwn[d] == g0) & (gwn[32 + d] == g0) &
                  (gwn[64 + d] == g0) & (gwn[96 + d] == g0);
        #pragma unroll
        for (int m = 1; m < 32; m <<= 1) {
            eqb &= __shfl_xor(eqb, m);
            eqg &= __shfl_xor(eqg, m);
        }
        if (d == 0) ws_u[n] = make_float4(eqb ? 1.f : 0.f, b0, eqg ? 1.f : 0.f, g0);
    }
}

// ===========================================================================
// Phase 2: one scan step. One thread per (b,n,d) -> 2048 blocks (2x TLP).
// Uniform-bw/gw fast path skips all weight loads (~55 VMEM ops vs ~200).
// Separate dispatch per step = global barrier + warm L2.
// ===========================================================================
__global__ __launch_bounds__(256) void step_kernel(
    const float*  __restrict__ msg_prev,  // (BS,N,D)
    float*        __restrict__ msg_out,   // (BS,N,D)
    const float*  __restrict__ h_in,      // (BS,N,D)
    float*        __restrict__ h_out,     // (BS,N,D)
    const float*  __restrict__ ws_ed,     // (BS,N)
    const float*  __restrict__ ws_ep,     // (BS,N,D)
    const float*  __restrict__ ws_rt,     // (BS,N,K)
    const float4* __restrict__ ws_u,      // (N)
    const float*  __restrict__ bw,        // (N,K,D)
    const float*  __restrict__ gw,        // (N,4,32)
    const float*  __restrict__ cc,        // (BS,T,C,D)
    const int*    __restrict__ conn,      // (N,K)
    float*        __restrict__ out,       // (BS,T,C,D)
    int step)
{
    const int g    = blockIdx.x * 256 + threadIdx.x;  // over BS*N*D
    const int d    = g & 31;
    const int pair = g >> 5;              // b*N + n
    const int n    = pair & (N - 1);
    const int b    = pair >> 13;

    const float4 u = ws_u[n];
    const int4*   jp = reinterpret_cast<const int4*>(conn + n * K);
    const float4* rp = reinterpret_cast<const float4*>(ws_rt + (size_t)pair * K);
    const float*  mp = msg_prev + (size_t)b * N * D;

    float bs[4] = {0.f, 0.f, 0.f, 0.f};
    if (u.x != 0.0f) {
        // uniform branch weights: bs[a] = w0 * sum_k rt*msg
        #pragma unroll
        for (int kk = 0; kk < 8; ++kk) {
            const int4   j4 = jp[kk];
            const float4 r4 = rp[kk];
            const int a = kk >> 1;
            bs[a] += r4.x * mp[(size_t)j4.x * D + d];
            bs[a] += r4.y * mp[(size_t)j4.y * D + d];
            bs[a] += r4.z * mp[(size_t)j4.z * D + d];
            bs[a] += r4.w * mp[(size_t)j4.w * D + d];
        }
        #pragma unroll
        for (int a = 0; a < 4; ++a) bs[a] *= u.y;
    } else {
        const float* bwn = bw + (size_t)n * (K * D);
        #pragma unroll
        for (int kk = 0; kk < 8; ++kk) {
            const int4   j4 = jp[kk];
            const float4 r4 = rp[kk];
            const int a = kk >> 1;
            bs[a] += r4.x * mp[(size_t)j4.x * D + d] * bwn[(4*kk+0)*32 + d];
            bs[a] += r4.y * mp[(size_t)j4.y * D + d] * bwn[(4*kk+1)*32 + d];
            bs[a] += r4.z * mp[(size_t)j4.z * D + d] * bwn[(4*kk+2)*32 + d];
            bs[a] += r4.w * mp[(size_t)j4.w * D + d] * bwn[(4*kk+3)*32 + d];
        }
    }

    const float t0 = tanhf(bs[0]), t1 = tanhf(bs[1]),
                t2 = tanhf(bs[2]), t3 = tanhf(bs[3]);
    float gsum;
    if (u.z != 0.0f) {
        gsum = u.w * (t0 + t1 + t2 + t3);
    } else {
        const float* gwn = gw + (size_t)n * 128;
        gsum = t0*gwn[d] + t1*gwn[32+d] + t2*gwn[64+d] + t3*gwn[96+d];
    }
    float received = tanhf(gsum);

    const size_t tslot = (size_t)b * (T * C * D) +
                         (size_t)(step * STRIDE) * (C * D) + n * D + d;
    if (n < C) received += cc[tslot];

    const float ed = ws_ed[pair];
    const float h  = h_in[(size_t)pair * D + d];
    const float hn = ed * h + (1.f - ed) * received;
    h_out[(size_t)pair * D + d] = hn;

    const float msg = tanhf(hn * ws_ep[(size_t)pair * D + d]);
    msg_out[(size_t)pair * D + d] = msg;

    if (n < C) {
        #pragma unroll
        for (int r = 0; r < STRIDE; ++r) out[tslot + (size_t)r * (C * D)] = msg;
    }
}

// ===========================================================================
extern "C" void kernel_launch(void* const* d_in, const int* in_sizes, int n_in,
                              void* d_out, int out_size, void* d_ws, size_t ws_size,
                              hipStream_t stream) {
    const float* cc          = (const float*)d_in[0];
    const float* h_prev      = (const float*)d_in[1];
    const float* prev_msgs   = (const float*)d_in[2];
    const float* trace_prim  = (const float*)d_in[3];
    const float* trace_key   = (const float*)d_in[4];
    const float* primitives  = (const float*)d_in[5];
    const float* key_w       = (const float*)d_in[6];
    const float* decay_logit = (const float*)d_in[7];
    const float* bw          = (const float*)d_in[8];
    const float* gw          = (const float*)d_in[9];
    const float* fc1_w       = (const float*)d_in[10];
    const float* fc1_b       = (const float*)d_in[11];
    const float* fc2_w       = (const float*)d_in[12];
    const float* fc2_b       = (const float*)d_in[13];
    const float* mod_lr      = (const float*)d_in[14];
    const int*   conn        = (const int*)d_in[15];
    // d_in[16] = stride (4, baked into STRIDE)

    float* ws     = (float*)d_ws;
    float* ws_ed  = ws;                       // BS*N
    float* ws_ep  = ws_ed + BS * N;           // BS*N*D
    float* ws_rt  = ws_ep + BS * N * D;       // BS*N*K
    float* ws_h   = ws_rt + BS * N * K;       // BS*N*D
    float* ws_m0  = ws_h  + BS * N * D;       // BS*N*D
    float* ws_m1  = ws_m0 + BS * N * D;       // BS*N*D
    float4* ws_u  = (float4*)(ws_m1 + BS * N * D);  // N float4
    float* outp   = (float*)d_out;

    phase1_kernel<<<N / NPB, 256, 0, stream>>>(
        h_prev, prev_msgs, trace_prim, trace_key, primitives, key_w,
        decay_logit, bw, gw, fc1_w, fc1_b, fc2_w, fc2_b, mod_lr, conn,
        ws_ed, ws_ep, ws_rt, ws_u);

    const int sb = (BS * N * D) / 256;  // 2048 blocks
    step_kernel<<<sb, 256, 0, stream>>>(prev_msgs, ws_m0, h_prev, ws_h,
        ws_ed, ws_ep, ws_rt, ws_u, bw, gw, cc, conn, outp, 0);
    step_kernel<<<sb, 256, 0, stream>>>(ws_m0, ws_m1, ws_h, ws_h,
        ws_ed, ws_ep, ws_rt, ws_u, bw, gw, cc, conn, outp, 1);
    step_kernel<<<sb, 256, 0, stream>>>(ws_m1, ws_m0, ws_h, ws_h,
        ws_ed, ws_ep, ws_rt, ws_u, bw, gw, cc, conn, outp, 2);
    step_kernel<<<sb, 256, 0, stream>>>(ws_m0, ws_m1, ws_h, ws_h,
        ws_ed, ws_ep, ws_rt, ws_u, bw, gw, cc, conn, outp, 3);
}

// Round 8
// 65.526 us; speedup vs baseline: 5.6001x; 1.1232x over previous
//
#include <hip/hip_runtime.h>

// Problem constants (MemoryGraph_15453292331249)
constexpr int N  = 8192;
constexpr int K  = 32;
constexpr int D  = 32;
constexpr int BS = 2;
constexpr int T  = 16;
constexpr int C  = 64;
constexpr int H  = 64;
constexpr int MOD_IN = 5 * D;   // 160
constexpr int STRIDE = 4;
constexpr int NPB = 8;          // neurons (32-lane groups) per block
constexpr int LIST_LEN = C * (K + 1);   // 2112 (with benign duplicates)

__device__ __forceinline__ float sigmoidf_(float x) { return 1.0f / (1.0f + expf(-x)); }

// ===========================================================================
// Phase 1 (+ fused scan step 0): 1024 blocks x 256 threads; 32-lane group
// owns one neuron. zcheck -> o3 -> gates/ed/ep/ek -> bw/gw uniformity check
// -> per-b { routing (stash neighbor rows in LDS) ; step-0 compute }.
// Also emits the step-2 active-neuron list (deterministic slots, no atomics):
// list[n*33+k] = conn[n,k], list[n*33+32] = n, for n < C.
// ===========================================================================
__global__ __launch_bounds__(256) void phase1_step0_kernel(
    const float* __restrict__ cc,          // (BS,T,C,D)
    const float* __restrict__ h_prev,      // (BS,N,D)
    const float* __restrict__ prev_msgs,   // (BS,N,D)
    const float* __restrict__ trace_prim,  // (BS,N,D)
    const float* __restrict__ trace_key,   // (BS,N,D)
    const float* __restrict__ primitives,  // (N,D)
    const float* __restrict__ key_w,       // (N,D)
    const float* __restrict__ decay_logit, // (N,)
    const float* __restrict__ bw,          // (N,K,D)
    const float* __restrict__ gw,          // (N,4,32)
    const float* __restrict__ fc1_w,       // (N,160,64)
    const float* __restrict__ fc1_b,       // (N,64)
    const float* __restrict__ fc2_w,       // (N,64,3)
    const float* __restrict__ fc2_b,       // (N,3)
    const float* __restrict__ mod_lr_logit,// (1,)
    const int*   __restrict__ conn,        // (N,K)
    float*  __restrict__ ws_ed,            // (BS,N)
    float*  __restrict__ ws_ep,            // (BS,N,D)
    float*  __restrict__ ws_rt,            // (BS,N,K)
    float4* __restrict__ ws_u,             // (N) {bw_uni, w0, gw_uni, g0}
    float*  __restrict__ ws_h,             // (BS,N,D)
    float*  __restrict__ ws_m0,            // (BS,N,D) msgs after step 0
    int*    __restrict__ ws_list,          // (LIST_LEN)
    float*  __restrict__ out)              // (BS,T,C,D)
{
    const int t   = threadIdx.x;
    const int sub = t >> 5;
    const int d   = t & 31;
    const int n   = blockIdx.x * NPB + sub;

    __shared__ __align__(16) float ek_s[NPB][2][D];
    __shared__ __align__(16) float rows[NPB][K][36];   // 36: 16B-aligned rows, ≤4-way
    __shared__ float rts[NPB][K];

    // ---- per-neuron fc2_w slice zero-check (skip multiply-by-zero; data-driven)
    const float* f2w = fc2_w + n * (H * 3);
    int nzf = 0;
    #pragma unroll
    for (int i = 0; i < 6; ++i) nzf |= (f2w[i * 32 + d] != 0.0f);
    #pragma unroll
    for (int m = 1; m < 32; m <<= 1) nzf |= __shfl_xor(nzf, m);

    float o3[2][3];
    if (!nzf) {
        #pragma unroll
        for (int o = 0; o < 3; ++o) {
            const float v = fc2_b[n * 3 + o];
            o3[0][o] = v; o3[1][o] = v;
        }
    } else {
        // General path: full fc1 matvec + fc2 (lane computes h=d and h=d+32).
        const float* W = fc1_w + (size_t)n * (MOD_IN * H);
        #pragma unroll
        for (int b = 0; b < 2; ++b) {
            const size_t base = ((size_t)b * N + n) * D + d;
            float mv[5];
            mv[0] = h_prev[base];
            mv[1] = trace_prim[base];
            mv[2] = trace_key[base];
            mv[3] = primitives[n * D + d];
            mv[4] = key_w[n * D + d];
            float acc0 = 0.f, acc1 = 0.f;
            #pragma unroll
            for (int c = 0; c < 5; ++c) {
                const float mc = mv[c];
                for (int dp = 0; dp < 32; ++dp) {
                    const float v = __shfl(mc, dp, 32);
                    const float* wr = W + (c * 32 + dp) * H;
                    acc0 += v * wr[d];
                    acc1 += v * wr[d + 32];
                }
            }
            const float x0 = tanhf(acc0 + fc1_b[n * H + d]);
            const float x1 = tanhf(acc1 + fc1_b[n * H + d + 32]);
            #pragma unroll
            for (int o = 0; o < 3; ++o) {
                float p = x0 * f2w[d * 3 + o] + x1 * f2w[(d + 32) * 3 + o];
                #pragma unroll
                for (int m = 1; m < 32; m <<= 1) p += __shfl_xor(p, m);
                o3[b][o] = p + fc2_b[n * 3 + o];
            }
        }
    }

    // ---- gates, eff_decay, eff_prim, eff_key
    const float mlr = sigmoidf_(mod_lr_logit[0]);
    float ep2[2], edc[2];
    #pragma unroll
    for (int b = 0; b < 2; ++b) {
        const size_t base = ((size_t)b * N + n) * D + d;
        const float tp = trace_prim[base];
        const float tk = trace_key[base];
        float sp = tp * tp, sk = tk * tk;
        #pragma unroll
        for (int m = 1; m < 32; m <<= 1) {
            sp += __shfl_xor(sp, m);
            sk += __shfl_xor(sk, m);
        }
        const float gate_prim = tanhf(o3[b][0]);
        const float gate_key  = tanhf(o3[b][1]);
        edc[b] = sigmoidf_(decay_logit[n] + o3[b][2]);
        if (d == 0) ws_ed[b * N + n] = edc[b];
        ep2[b] = primitives[n*D+d] + mlr*gate_prim*(tp / fmaxf(sqrtf(sp), 1e-8f));
        const float ekv = key_w[n*D+d] + mlr*gate_key *(tk / fmaxf(sqrtf(sk), 1e-8f));
        ws_ep[base] = ep2[b];
        ek_s[sub][b][d] = ekv;
    }

    // ---- bw/gw per-neuron uniformity check (coalesced; lane-AND reduce)
    const float* bwn = bw + (size_t)n * (K * D);
    const float* gwn = gw + (size_t)n * 128;
    const float w0v = bwn[0];
    const float g0v = gwn[0];
    int eqb = 1;
    #pragma unroll
    for (int k = 0; k < 32; ++k) eqb &= (bwn[k * 32 + d] == w0v);
    int eqg = (gwn[d] == g0v) & (gwn[32 + d] == g0v) &
              (gwn[64 + d] == g0v) & (gwn[96 + d] == g0v);
    #pragma unroll
    for (int m = 1; m < 32; m <<= 1) {
        eqb &= __shfl_xor(eqb, m);
        eqg &= __shfl_xor(eqg, m);
    }
    if (d == 0) ws_u[n] = make_float4(eqb ? 1.f : 0.f, w0v, eqg ? 1.f : 0.f, g0v);

    // ---- step-2 active list (deterministic, no atomics)
    if (n < C) {
        ws_list[n * (K + 1) + d] = conn[n * K + d];
        if (d == 0) ws_list[n * (K + 1) + K] = n;
    }

    // ---- fused scan step 0 (routing gather doubles as the message gather)
    const float gv0 = gwn[d], gv1 = gwn[32+d], gv2 = gwn[64+d], gv3 = gwn[96+d];
    #pragma unroll
    for (int b = 0; b < 2; ++b) {
        __syncthreads();   // rows reuse across b + ek_s ready
        {   // lane acts as k
            const int k = d;
            const int j = conn[n * K + k];
            const float4* pm = reinterpret_cast<const float4*>(
                prev_msgs + ((size_t)b * N + j) * D);
            float4 v[8];
            float s = 0.f;
            #pragma unroll
            for (int q = 0; q < 8; ++q) {
                v[q] = pm[q];
                s += ek_s[sub][b][q*4+0]*v[q].x + ek_s[sub][b][q*4+1]*v[q].y +
                     ek_s[sub][b][q*4+2]*v[q].z + ek_s[sub][b][q*4+3]*v[q].w;
            }
            const float rtv = sigmoidf_(s);
            ws_rt[((size_t)b * N + n) * K + k] = rtv;
            rts[sub][k] = rtv;
            #pragma unroll
            for (int q = 0; q < 8; ++q)
                *reinterpret_cast<float4*>(&rows[sub][k][q*4]) = v[q];
        }
        __syncthreads();
        {   // lane acts as d
            float bs[4] = {0.f, 0.f, 0.f, 0.f};
            if (eqb) {
                #pragma unroll
                for (int k = 0; k < 32; ++k)
                    bs[k >> 3] += rts[sub][k] * rows[sub][k][d];
                #pragma unroll
                for (int a = 0; a < 4; ++a) bs[a] *= w0v;
            } else {
                #pragma unroll
                for (int k = 0; k < 32; ++k)
                    bs[k >> 3] += rts[sub][k] * rows[sub][k][d] * bwn[k * 32 + d];
            }
            const float t0 = tanhf(bs[0]), t1 = tanhf(bs[1]),
                        t2 = tanhf(bs[2]), t3 = tanhf(bs[3]);
            const float gsum = eqg ? g0v * (t0 + t1 + t2 + t3)
                                   : t0*gv0 + t1*gv1 + t2*gv2 + t3*gv3;
            float rec = tanhf(gsum);
            const size_t tslot = (size_t)b * (T * C * D) + (size_t)n * D + d;  // t=0
            if (n < C) rec += cc[tslot];
            const float hn = edc[b] * h_prev[((size_t)b * N + n) * D + d]
                           + (1.f - edc[b]) * rec;
            const float msg = tanhf(hn * ep2[b]);
            ws_h[((size_t)b * N + n) * D + d]  = hn;
            ws_m0[((size_t)b * N + n) * D + d] = msg;
            if (n < C) {
                #pragma unroll
                for (int r = 0; r < STRIDE; ++r)
                    out[tslot + (size_t)r * (C * D)] = msg;
            }
        }
    }
}

// ===========================================================================
// Full scan step (step 1): one thread per (b,n,d), 2048 blocks.
// ===========================================================================
__global__ __launch_bounds__(256) void step_kernel(
    const float*  __restrict__ msg_prev, float* __restrict__ msg_out,
    const float*  __restrict__ h_in, float* __restrict__ h_out,
    const float*  __restrict__ ws_ed, const float* __restrict__ ws_ep,
    const float*  __restrict__ ws_rt, const float4* __restrict__ ws_u,
    const float*  __restrict__ bw, const float* __restrict__ gw,
    const float*  __restrict__ cc, const int* __restrict__ conn,
    float*        __restrict__ out, int step)
{
    const int g    = blockIdx.x * 256 + threadIdx.x;
    const int d    = g & 31;
    const int pair = g >> 5;
    const int n    = pair & (N - 1);
    const int b    = pair >> 13;

    const float4 u = ws_u[n];
    const int4*   jp = reinterpret_cast<const int4*>(conn + n * K);
    const float4* rp = reinterpret_cast<const float4*>(ws_rt + (size_t)pair * K);
    const float*  mp = msg_prev + (size_t)b * N * D;

    float bs[4] = {0.f, 0.f, 0.f, 0.f};
    if (u.x != 0.0f) {
        #pragma unroll
        for (int kk = 0; kk < 8; ++kk) {
            const int4 j4 = jp[kk]; const float4 r4 = rp[kk];
            const int a = kk >> 1;
            bs[a] += r4.x * mp[(size_t)j4.x * D + d];
            bs[a] += r4.y * mp[(size_t)j4.y * D + d];
            bs[a] += r4.z * mp[(size_t)j4.z * D + d];
            bs[a] += r4.w * mp[(size_t)j4.w * D + d];
        }
        #pragma unroll
        for (int a = 0; a < 4; ++a) bs[a] *= u.y;
    } else {
        const float* bwn = bw + (size_t)n * (K * D);
        #pragma unroll
        for (int kk = 0; kk < 8; ++kk) {
            const int4 j4 = jp[kk]; const float4 r4 = rp[kk];
            const int a = kk >> 1;
            bs[a] += r4.x * mp[(size_t)j4.x * D + d] * bwn[(4*kk+0)*32 + d];
            bs[a] += r4.y * mp[(size_t)j4.y * D + d] * bwn[(4*kk+1)*32 + d];
            bs[a] += r4.z * mp[(size_t)j4.z * D + d] * bwn[(4*kk+2)*32 + d];
            bs[a] += r4.w * mp[(size_t)j4.w * D + d] * bwn[(4*kk+3)*32 + d];
        }
    }

    const float t0 = tanhf(bs[0]), t1 = tanhf(bs[1]),
                t2 = tanhf(bs[2]), t3 = tanhf(bs[3]);
    float gsum;
    if (u.z != 0.0f) gsum = u.w * (t0 + t1 + t2 + t3);
    else {
        const float* gwn = gw + (size_t)n * 128;
        gsum = t0*gwn[d] + t1*gwn[32+d] + t2*gwn[64+d] + t3*gwn[96+d];
    }
    float received = tanhf(gsum);

    const size_t tslot = (size_t)b * (T * C * D) +
                         (size_t)(step * STRIDE) * (C * D) + n * D + d;
    if (n < C) received += cc[tslot];

    const float ed = ws_ed[pair];
    const float hn = ed * h_in[(size_t)pair * D + d] + (1.f - ed) * received;
    h_out[(size_t)pair * D + d] = hn;
    const float msg = tanhf(hn * ws_ep[(size_t)pair * D + d]);
    msg_out[(size_t)pair * D + d] = msg;

    if (n < C) {
        #pragma unroll
        for (int r = 0; r < STRIDE; ++r) out[tslot + (size_t)r * (C * D)] = msg;
    }
}

// ===========================================================================
// Sparse scan step (steps 2,3): only neurons whose results are ever read.
// NLIST=LIST_LEN with n=list[e] (step 2), or NLIST=C with n=e (step 3).
// ===========================================================================
template<bool USE_LIST>
__global__ __launch_bounds__(256) void step_sparse_kernel(
    const float*  __restrict__ msg_prev, float* __restrict__ msg_out,
    const float*  __restrict__ h_in, float* __restrict__ h_out,
    const float*  __restrict__ ws_ed, const float* __restrict__ ws_ep,
    const float*  __restrict__ ws_rt, const float4* __restrict__ ws_u,
    const float*  __restrict__ bw, const float* __restrict__ gw,
    const float*  __restrict__ cc, const int* __restrict__ conn,
    const int*    __restrict__ ws_list,
    float*        __restrict__ out, int step)
{
    const int i = blockIdx.x * 256 + threadIdx.x;
    const int e = i >> 6;                 // entry
    const int d = i & 31;
    const int b = (i >> 5) & 1;
    const int n = USE_LIST ? ws_list[e] : e;
    const int pair = b * N + n;

    const float4 u = ws_u[n];
    const int4*   jp = reinterpret_cast<const int4*>(conn + n * K);
    const float4* rp = reinterpret_cast<const float4*>(ws_rt + (size_t)pair * K);
    const float*  mp = msg_prev + (size_t)b * N * D;

    float bs[4] = {0.f, 0.f, 0.f, 0.f};
    if (u.x != 0.0f) {
        #pragma unroll
        for (int kk = 0; kk < 8; ++kk) {
            const int4 j4 = jp[kk]; const float4 r4 = rp[kk];
            const int a = kk >> 1;
            bs[a] += r4.x * mp[(size_t)j4.x * D + d];
            bs[a] += r4.y * mp[(size_t)j4.y * D + d];
            bs[a] += r4.z * mp[(size_t)j4.z * D + d];
            bs[a] += r4.w * mp[(size_t)j4.w * D + d];
        }
        #pragma unroll
        for (int a = 0; a < 4; ++a) bs[a] *= u.y;
    } else {
        const float* bwn = bw + (size_t)n * (K * D);
        #pragma unroll
        for (int kk = 0; kk < 8; ++kk) {
            const int4 j4 = jp[kk]; const float4 r4 = rp[kk];
            const int a = kk >> 1;
            bs[a] += r4.x * mp[(size_t)j4.x * D + d] * bwn[(4*kk+0)*32 + d];
            bs[a] += r4.y * mp[(size_t)j4.y * D + d] * bwn[(4*kk+1)*32 + d];
            bs[a] += r4.z * mp[(size_t)j4.z * D + d] * bwn[(4*kk+2)*32 + d];
            bs[a] += r4.w * mp[(size_t)j4.w * D + d] * bwn[(4*kk+3)*32 + d];
        }
    }

    const float t0 = tanhf(bs[0]), t1 = tanhf(bs[1]),
                t2 = tanhf(bs[2]), t3 = tanhf(bs[3]);
    float gsum;
    if (u.z != 0.0f) gsum = u.w * (t0 + t1 + t2 + t3);
    else {
        const float* gwn = gw + (size_t)n * 128;
        gsum = t0*gwn[d] + t1*gwn[32+d] + t2*gwn[64+d] + t3*gwn[96+d];
    }
    float received = tanhf(gsum);

    const size_t tslot = (size_t)b * (T * C * D) +
                         (size_t)(step * STRIDE) * (C * D) + n * D + d;
    if (n < C) received += cc[tslot];

    const float ed = ws_ed[pair];
    const float hn = ed * h_in[(size_t)pair * D + d] + (1.f - ed) * received;
    h_out[(size_t)pair * D + d] = hn;
    const float msg = tanhf(hn * ws_ep[(size_t)pair * D + d]);
    msg_out[(size_t)pair * D + d] = msg;

    if (n < C) {
        #pragma unroll
        for (int r = 0; r < STRIDE; ++r) out[tslot + (size_t)r * (C * D)] = msg;
    }
}

// ===========================================================================
extern "C" void kernel_launch(void* const* d_in, const int* in_sizes, int n_in,
                              void* d_out, int out_size, void* d_ws, size_t ws_size,
                              hipStream_t stream) {
    const float* cc          = (const float*)d_in[0];
    const float* h_prev      = (const float*)d_in[1];
    const float* prev_msgs   = (const float*)d_in[2];
    const float* trace_prim  = (const float*)d_in[3];
    const float* trace_key   = (const float*)d_in[4];
    const float* primitives  = (const float*)d_in[5];
    const float* key_w       = (const float*)d_in[6];
    const float* decay_logit = (const float*)d_in[7];
    const float* bw          = (const float*)d_in[8];
    const float* gw          = (const float*)d_in[9];
    const float* fc1_w       = (const float*)d_in[10];
    const float* fc1_b       = (const float*)d_in[11];
    const float* fc2_w       = (const float*)d_in[12];
    const float* fc2_b       = (const float*)d_in[13];
    const float* mod_lr      = (const float*)d_in[14];
    const int*   conn        = (const int*)d_in[15];
    // d_in[16] = stride (4, baked into STRIDE)

    float* ws     = (float*)d_ws;
    float* ws_ed  = ws;                       // BS*N
    float* ws_ep  = ws_ed + BS * N;           // BS*N*D
    float* ws_rt  = ws_ep + BS * N * D;       // BS*N*K
    float* ws_h   = ws_rt + BS * N * K;       // BS*N*D
    float* ws_m0  = ws_h  + BS * N * D;       // BS*N*D
    float* ws_m1  = ws_m0 + BS * N * D;       // BS*N*D
    float4* ws_u  = (float4*)(ws_m1 + BS * N * D);  // N float4
    int*   ws_list = (int*)(ws_u + N);        // LIST_LEN
    float* outp   = (float*)d_out;

    phase1_step0_kernel<<<N / NPB, 256, 0, stream>>>(
        cc, h_prev, prev_msgs, trace_prim, trace_key, primitives, key_w,
        decay_logit, bw, gw, fc1_w, fc1_b, fc2_w, fc2_b, mod_lr, conn,
        ws_ed, ws_ep, ws_rt, ws_u, ws_h, ws_m0, ws_list, outp);

    // step 1: full
    step_kernel<<<(BS * N * D) / 256, 256, 0, stream>>>(
        ws_m0, ws_m1, ws_h, ws_h, ws_ed, ws_ep, ws_rt, ws_u,
        bw, gw, cc, conn, outp, 1);

    // step 2: only neurons in conn[:C] ∪ [:C]  (2112 entries incl. duplicates)
    step_sparse_kernel<true><<<(LIST_LEN * 64) / 256, 256, 0, stream>>>(
        ws_m1, ws_m0, ws_h, ws_h, ws_ed, ws_ep, ws_rt, ws_u,
        bw, gw, cc, conn, ws_list, outp, 2);

    // step 3: only neurons [:C]
    step_sparse_kernel<false><<<(C * 64) / 256, 256, 0, stream>>>(
        ws_m0, ws_m1, ws_h, ws_h, ws_ed, ws_ep, ws_rt, ws_u,
        bw, gw, cc, conn, ws_list, outp, 3);
}